// Round 1
// 573.817 us; speedup vs baseline: 1.1208x; 1.1208x over previous
//
#include <hip/hip_runtime.h>

// Problem constants (from reference setup_inputs): B=4, T=512, U=128, D=512, V=512
#define B_ 4
#define T_ 512
#define U_ 128
#define D_ 512
#define V_ 512
#define MS (B_ * T_)          // 2048 speech rows
#define MT (B_ * U_)          // 512 text rows
#define MTOT (MS + MT)        // 2560
#define LOGITS_ELEMS ((size_t)B_ * T_ * U_ * V_)   // 134217728

// GEMM tiling: 128x64 output tile, 256 threads, 8x4 per thread, K-tile 32.
// LDS holds TRANSPOSED tiles (k-major) so the inner loop is an outer product:
//   a-reads: 4 distinct 16B segments/wave (16-way broadcast)  -> conflict-free
//   b-reads: 64 consecutive floats/wave (2 bank wraps)        -> 2-way = free
// This removes the 8-way ds_read_b128 conflict of the previous float4-over-k
// layout (stride mult-of-4 floats forces 4S mod 32 in {0,16} -> unavoidable).
#define TM 128
#define TN 64
#define TK 32
#define NTILES (D_ / TK)      // 16
#define XSTR 132              // Xt row stride (floats): 128 + 4, keeps 16B align
#define WSTR 68               // Wt row stride (floats): 64 + 4

typedef float f32x4 __attribute__((ext_vector_type(4)));

// Kernel 1: C = X * W^T for X = concat(speech [2048,512], text [512,512]).
// Speech rows -> S (no bias), text rows -> Tx (+bias).
// Grid (20, 8): MTOT/TM x V_/TN. 2048 % TM == 0, so each block is purely
// speech or purely text.
__global__ __launch_bounds__(256, 2) void gemm_joint(
    const float* __restrict__ speech, const float* __restrict__ text,
    const float* __restrict__ W, const float* __restrict__ bias,
    float* __restrict__ S, float* __restrict__ Tx)
{
    __shared__ float Xt[TK][XSTR];   // Xt[k][m]
    __shared__ float Wt[TK][WSTR];   // Wt[k][n]

    const int tid = threadIdx.x;
    const int m0 = blockIdx.x * TM;
    const int n0 = blockIdx.y * TN;
    const int tx = tid & 15;         // n: 16 groups of 4 cols
    const int ty = tid >> 4;         // m: 16 groups of 8 rows

    const float* xbase = (m0 < MS) ? (speech + (size_t)m0 * D_)
                                   : (text + (size_t)(m0 - MS) * D_);

    float acc[8][4] = {};
    float4 xr[4], wr[2];

    // ---- prologue: load + transpose-store K-tile 0 ----
    #pragma unroll
    for (int i = 0; i < 4; ++i) {
        const int q = tid + 256 * i;                  // 0..1023 float4s of X tile
        xr[i] = *(const float4*)(xbase + (size_t)(q >> 3) * D_ + ((q & 7) << 2));
    }
    #pragma unroll
    for (int i = 0; i < 2; ++i) {
        const int q = tid + 256 * i;                  // 0..511 float4s of W tile
        wr[i] = *(const float4*)(W + (size_t)(n0 + (q >> 3)) * D_ + ((q & 7) << 2));
    }
    #pragma unroll
    for (int i = 0; i < 4; ++i) {
        const int q = tid + 256 * i;
        const int r = q >> 3, c = (q & 7) << 2;
        Xt[c + 0][r] = xr[i].x; Xt[c + 1][r] = xr[i].y;
        Xt[c + 2][r] = xr[i].z; Xt[c + 3][r] = xr[i].w;
    }
    #pragma unroll
    for (int i = 0; i < 2; ++i) {
        const int q = tid + 256 * i;
        const int r = q >> 3, c = (q & 7) << 2;
        Wt[c + 0][r] = wr[i].x; Wt[c + 1][r] = wr[i].y;
        Wt[c + 2][r] = wr[i].z; Wt[c + 3][r] = wr[i].w;
    }
    __syncthreads();

    for (int t = 0; t < NTILES; ++t) {
        // register-prefetch the next K-tile across the compute phase
        if (t + 1 < NTILES) {
            const int kn = (t + 1) * TK;
            #pragma unroll
            for (int i = 0; i < 4; ++i) {
                const int q = tid + 256 * i;
                xr[i] = *(const float4*)(xbase + (size_t)(q >> 3) * D_ + kn + ((q & 7) << 2));
            }
            #pragma unroll
            for (int i = 0; i < 2; ++i) {
                const int q = tid + 256 * i;
                wr[i] = *(const float4*)(W + (size_t)(n0 + (q >> 3)) * D_ + kn + ((q & 7) << 2));
            }
        }

        // outer-product compute over the 32 k of this tile
        #pragma unroll 8
        for (int k = 0; k < TK; ++k) {
            const float4 a0 = *(const float4*)&Xt[k][ty * 8];
            const float4 a1 = *(const float4*)&Xt[k][ty * 8 + 4];
            const float4 b0 = *(const float4*)&Wt[k][tx * 4];
            const float av[8] = {a0.x, a0.y, a0.z, a0.w, a1.x, a1.y, a1.z, a1.w};
            const float bv[4] = {b0.x, b0.y, b0.z, b0.w};
            #pragma unroll
            for (int i = 0; i < 8; ++i)
                #pragma unroll
                for (int j = 0; j < 4; ++j)
                    acc[i][j] += av[i] * bv[j];
        }

        if (t + 1 < NTILES) {
            __syncthreads();   // all reads of old tile done
            #pragma unroll
            for (int i = 0; i < 4; ++i) {
                const int q = tid + 256 * i;
                const int r = q >> 3, c = (q & 7) << 2;
                Xt[c + 0][r] = xr[i].x; Xt[c + 1][r] = xr[i].y;
                Xt[c + 2][r] = xr[i].z; Xt[c + 3][r] = xr[i].w;
            }
            #pragma unroll
            for (int i = 0; i < 2; ++i) {
                const int q = tid + 256 * i;
                const int r = q >> 3, c = (q & 7) << 2;
                Wt[c + 0][r] = wr[i].x; Wt[c + 1][r] = wr[i].y;
                Wt[c + 2][r] = wr[i].z; Wt[c + 3][r] = wr[i].w;
            }
            __syncthreads();   // new tile visible
        }
    }

    // ---- epilogue: float4 stores; fold bias into the text rows (Tx) ----
    const int vbase = n0 + tx * 4;
    #pragma unroll
    for (int i = 0; i < 8; ++i) {
        const int m = m0 + ty * 8 + i;
        float4 o;
        o.x = acc[i][0]; o.y = acc[i][1]; o.z = acc[i][2]; o.w = acc[i][3];
        if (m < MS) {
            *(float4*)(S + (size_t)m * V_ + vbase) = o;
        } else {
            o.x += bias[vbase + 0];
            o.y += bias[vbase + 1];
            o.z += bias[vbase + 2];
            o.w += bias[vbase + 3];
            *(float4*)(Tx + (size_t)(m - MS) * V_ + vbase) = o;
        }
    }
}

// Kernel 2: out[b,t,u,v] = S[b*T+t, v] + Tx[b*U+u, v]   (bias already in Tx)
// One block per (b,t): writes a contiguous 256KB region. Non-temporal stores
// keep the 537MB output stream from thrashing the L2 that serves Tx re-reads.
// Also folds the lens-append (was a 3rd kernel) into block 0.
__global__ __launch_bounds__(256, 8) void bcast_add(
    const float* __restrict__ S, const float* __restrict__ Tx,
    const int* __restrict__ sl, const int* __restrict__ tl,
    float* __restrict__ out)
{
    const int V4 = V_ / 4;                  // 128
    const int bt = blockIdx.x;              // 0..2047
    const int b  = bt >> 9;                 // bt / T_
    const int tid = threadIdx.x;

    if (bt == 0 && tid < 2 * B_) {
        out[LOGITS_ELEMS + tid] = (tid < B_) ? (float)sl[tid]
                                             : (float)tl[tid - B_];
    }

    const f32x4* S4 = (const f32x4*)S + (size_t)bt * V4;
    const f32x4* T4 = (const f32x4*)Tx + (size_t)b * U_ * V4;
    f32x4* O4 = (f32x4*)out + (size_t)bt * U_ * V4;

    // idx % 128 == tid % 128 for every iteration -> S row element is loop-invariant
    const f32x4 sv = S4[tid & (V4 - 1)];

    #pragma unroll 8
    for (int idx = tid; idx < U_ * V4; idx += 256) {
        const f32x4 tv = T4[idx];
        __builtin_nontemporal_store(sv + tv, &O4[idx]);
    }
}

extern "C" void kernel_launch(void* const* d_in, const int* in_sizes, int n_in,
                              void* d_out, int out_size, void* d_ws, size_t ws_size,
                              hipStream_t stream) {
    const float* speech = (const float*)d_in[0];
    const float* text   = (const float*)d_in[1];
    const float* W      = (const float*)d_in[2];
    const float* bias   = (const float*)d_in[3];
    const int*   sl     = (const int*)d_in[4];
    const int*   tl     = (const int*)d_in[5];
    float* out = (float*)d_out;

    float* S  = (float*)d_ws;                 // [2048, 512]  (4 MB)
    float* Tx = S + (size_t)MS * V_;          // [512, 512]   (1 MB)

    dim3 g1(MTOT / TM, V_ / TN);              // 20 x 8 = 160 blocks
    gemm_joint<<<g1, 256, 0, stream>>>(speech, text, W, bias, S, Tx);

    bcast_add<<<MS, 256, 0, stream>>>(S, Tx, sl, tl, out);   // 2048 blocks
}